// Round 16
// baseline (76.586 us; speedup 1.0000x reference)
//
#include <hip/hip_runtime.h>

// GNN layer: out = segment_sum(feat[src], dst) @ W^T + b
// Round 16: partition-targeted probe.  Round 13-15 subtraction pins the
// partition half of prep at ~30us (245 clustered blocks, ~1/CU, serialized
// atomic chains).  Changes vs round 15 (ONLY partition-side):
//   - PART_T 4096 -> 2048 (489 tiles; halves per-block serial work)
//   - partition tiles interleaved across blockIdx (every 4th block) so they
//     spread round-robin over CUs instead of clustering at the front.
// Everything else identical: MFMA transform (A=W, B=feat, ushort4 stores),
// 64-node slabs, slot partition, shfl-scan counting-sort gather.

#define DIM 64
#define SLAB_SHIFT 6
#define SLAB_NODES 64
#define MAX_SLABS 1600    // >= ceil(100000/64) = 1563
#define SLAB_CAP 1024     // slot capacity per slab (avg 640, max ~754)
#define PART_T 2048       // edges per partition tile (489 tiles)

typedef __attribute__((ext_vector_type(8))) short bf16x8;
typedef __attribute__((ext_vector_type(4))) float f32x4;

__device__ __forceinline__ unsigned short f2bf(float x) {
    unsigned u = __float_as_uint(x);
    unsigned r = ((u >> 16) & 1u) + 0x7FFFu;     // round-to-nearest-even
    return (unsigned short)((u + r) >> 16);
}
__device__ __forceinline__ float bf2f(unsigned short h) {
    return __uint_as_float((unsigned)h << 16);
}
// Load 8 consecutive f32, convert to a bf16x8 MFMA fragment.
__device__ __forceinline__ bf16x8 cvt8(const float* p) {
    float4 x = *(const float4*)p;
    float4 y = *(const float4*)(p + 4);
    bf16x8 r;
    r[0] = (short)f2bf(x.x); r[1] = (short)f2bf(x.y);
    r[2] = (short)f2bf(x.z); r[3] = (short)f2bf(x.w);
    r[4] = (short)f2bf(y.x); r[5] = (short)f2bf(y.y);
    r[6] = (short)f2bf(y.z); r[7] = (short)f2bf(y.w);
    return r;
}

__global__ void zero_cursors(int* __restrict__ cursors) {
    int i = blockIdx.x * blockDim.x + threadIdx.x;
    if (i < MAX_SLABS) cursors[i] = 0;
}

// Fat kernel.  Partition tiles are interleaved: blockIdx r is a partition
// block iff (r&3)==0 && (r>>2)<ntiles; its tile is r>>2.  Otherwise it is a
// transform block with tile index r - min((r+3)>>2, ntiles).
__global__ void __launch_bounds__(256, 4)
prep_kernel(const float* __restrict__ feat, const float* __restrict__ W,
            unsigned short* __restrict__ g,
            const int* __restrict__ src, const int* __restrict__ dst,
            int* __restrict__ cursors, unsigned int* __restrict__ packed,
            int n_nodes, int n_edges, int ntiles) {
    __shared__ int cnt[MAX_SLABS];
    __shared__ int base_[MAX_SLABS];
    __shared__ int pos[MAX_SLABS];
    int tid = threadIdx.x;
    int r = blockIdx.x;
    bool is_part = ((r & 3) == 0) && ((r >> 2) < ntiles);

    if (is_part) {
        // ---------------- partition: one 2048-edge tile ----------------
        int t0 = (r >> 2) * PART_T;
        int m = min(PART_T, n_edges - t0);
        int m4 = m >> 2;
        int nslab = (n_nodes + SLAB_NODES - 1) / SLAB_NODES;
        for (int i = tid; i < nslab; i += 256) { cnt[i] = 0; pos[i] = 0; }
        __syncthreads();
        const int4* d4 = (const int4*)(dst + t0);
        for (int i = tid; i < m4; i += 256) {
            int4 d = d4[i];
            atomicAdd(&cnt[d.x >> SLAB_SHIFT], 1);
            atomicAdd(&cnt[d.y >> SLAB_SHIFT], 1);
            atomicAdd(&cnt[d.z >> SLAB_SHIFT], 1);
            atomicAdd(&cnt[d.w >> SLAB_SHIFT], 1);
        }
        if (tid < (m & 3)) atomicAdd(&cnt[dst[t0 + (m4 << 2) + tid] >> SLAB_SHIFT], 1);
        __syncthreads();
        for (int i = tid; i < nslab; i += 256) {
            int c = cnt[i];
            base_[i] = c ? atomicAdd(&cursors[i], c) : 0;
        }
        __syncthreads();
        const int4* s4 = (const int4*)(src + t0);
        for (int i = tid; i < m4; i += 256) {
            int4 d = d4[i];
            int4 s = s4[i];
            int sl, off;
            sl = d.x >> SLAB_SHIFT; off = base_[sl] + atomicAdd(&pos[sl], 1);
            if (off < SLAB_CAP)
                packed[sl * SLAB_CAP + off] =
                    ((unsigned)(d.x & (SLAB_NODES - 1)) << 25) | (unsigned)s.x;
            sl = d.y >> SLAB_SHIFT; off = base_[sl] + atomicAdd(&pos[sl], 1);
            if (off < SLAB_CAP)
                packed[sl * SLAB_CAP + off] =
                    ((unsigned)(d.y & (SLAB_NODES - 1)) << 25) | (unsigned)s.y;
            sl = d.z >> SLAB_SHIFT; off = base_[sl] + atomicAdd(&pos[sl], 1);
            if (off < SLAB_CAP)
                packed[sl * SLAB_CAP + off] =
                    ((unsigned)(d.z & (SLAB_NODES - 1)) << 25) | (unsigned)s.z;
            sl = d.w >> SLAB_SHIFT; off = base_[sl] + atomicAdd(&pos[sl], 1);
            if (off < SLAB_CAP)
                packed[sl * SLAB_CAP + off] =
                    ((unsigned)(d.w & (SLAB_NODES - 1)) << 25) | (unsigned)s.w;
        }
        if (tid < (m & 3)) {
            int e = t0 + (m4 << 2) + tid;
            int d = dst[e];
            int sl = d >> SLAB_SHIFT;
            int off = base_[sl] + atomicAdd(&pos[sl], 1);
            if (off < SLAB_CAP)
                packed[sl * SLAB_CAP + off] =
                    ((unsigned)(d & (SLAB_NODES - 1)) << 25) | (unsigned)src[e];
        }
    } else {
        // -------- transform: 64 rows per block, MFMA, no LDS --------
        // A = W rows (m = output col o), B = feat rows (n = node).
        // A/B frag: {m|n} = lane&15, k = (lane>>4)*8 + j.
        // D frag: n(node) = lane&15, m(o) = (lane>>4)*4 + reg
        //   -> per lane per mfma t: node fixed, 4 consecutive o's -> ushort4.
        int ttile = r - min((r + 3) >> 2, ntiles);
        int lane = tid & 63;
        int wv = tid >> 6;
        int base_node = ttile * 64 + wv * 16;
        int rl = lane & 15;
        int kb = (lane >> 4) * 8;

        int node = base_node + rl;          // B-frag row AND D-store node
        bf16x8 bLo, bHi;
        if (node < n_nodes) {
            const float* fr = feat + (long)node * DIM;
            bLo = cvt8(fr + kb);
            bHi = cvt8(fr + kb + 32);
        } else {
            bf16x8 z = {0, 0, 0, 0, 0, 0, 0, 0};
            bLo = z; bHi = z;
        }

        unsigned short* gp = g + (long)node * DIM + (lane >> 4) * 4;
#pragma unroll
        for (int t = 0; t < 4; ++t) {
            const float* wr = W + (long)(t * 16 + rl) * DIM;
            bf16x8 aLo = cvt8(wr + kb);
            bf16x8 aHi = cvt8(wr + kb + 32);
            f32x4 c = {0.f, 0.f, 0.f, 0.f};
            c = __builtin_amdgcn_mfma_f32_16x16x32_bf16(aLo, bLo, c, 0, 0, 0);
            c = __builtin_amdgcn_mfma_f32_16x16x32_bf16(aHi, bHi, c, 0, 0, 0);
            if (node < n_nodes) {
                ushort4 o4;
                o4.x = f2bf(c[0]); o4.y = f2bf(c[1]);
                o4.z = f2bf(c[2]); o4.w = f2bf(c[3]);
                *(ushort4*)(gp + t * 16) = o4;
            }
        }
    }
}

// One block per 64-node slab (512 threads = 64 eight-lane groups, 1 node per
// group).  Stage packed (uint4), LDS counting-sort by exact dst (shfl scan),
// then gather: lane reads uint4 = 8 bf16 of the g row, unroll 4, fp32
// accumulate, + bias, write out.
__global__ void __launch_bounds__(512, 8)
slab_gather(const unsigned short* __restrict__ g, const int* __restrict__ counts,
            const unsigned int* __restrict__ packed,
            const float* __restrict__ b, float* __restrict__ out, int n_nodes) {
    __shared__ unsigned int raw[SLAB_CAP];
    __shared__ int srt[SLAB_CAP];
    __shared__ int cnt[SLAB_NODES];         // counts -> cursors
    __shared__ int lstarts[SLAB_NODES + 1];
    int tid = threadIdx.x;
    int slab = blockIdx.x;
    int ce = min(counts[slab], SLAB_CAP);
    {   // vectorized staging (may read up to 3 extra in-capacity words)
        const uint4* pk4 = (const uint4*)(packed + (long)slab * SLAB_CAP);
        int ce4 = (ce + 3) >> 2;
        for (int k = tid; k < ce4; k += 512) ((uint4*)raw)[k] = pk4[k];
    }
    if (tid < SLAB_NODES) cnt[tid] = 0;
    __syncthreads();

    for (int k = tid; k < ce; k += 512) atomicAdd(&cnt[raw[k] >> 25], 1);
    __syncthreads();

    if (tid < 64) {      // single-wave exclusive scan of 64 bins
        int v = cnt[tid];
        int orig = v;
#pragma unroll
        for (int off = 1; off < 64; off <<= 1) {
            int x = __shfl_up(v, off, 64);
            v += (tid >= off) ? x : 0;
        }
        lstarts[tid + 1] = v;
        cnt[tid] = v - orig;               // exclusive cursor
        if (tid == 0) lstarts[0] = 0;
    }
    __syncthreads();

    for (int k = tid; k < ce; k += 512) {
        unsigned int v = raw[k];
        int nl = (int)(v >> 25);
        int p = atomicAdd(&cnt[nl], 1);
        srt[p] = (int)(v & 0x1FFFFFFu);
    }
    __syncthreads();

    int grp = tid >> 3;      // 0..63: owns node `grp` of the slab
    int part = tid & 7;      // uint4 chunk (8 bf16 columns)
    int node0 = slab * SLAB_NODES;
    int nsn = min(SLAB_NODES, n_nodes - node0);
    const uint4* g4 = (const uint4*)g;

    if (grp < nsn) {
        float4 accA = *(const float4*)(b + part * 8);
        float4 accB = *(const float4*)(b + part * 8 + 4);
        int a0 = lstarts[grp], a1 = lstarts[grp + 1];
        int e = a0;
        for (; e + 3 < a1; e += 4) {
            uint4 v0 = g4[(long)srt[e]     * 8 + part];
            uint4 v1 = g4[(long)srt[e + 1] * 8 + part];
            uint4 v2 = g4[(long)srt[e + 2] * 8 + part];
            uint4 v3 = g4[(long)srt[e + 3] * 8 + part];
#define ACC8(v)                                                          \
            accA.x += bf2f((unsigned short)(v.x & 0xFFFF));              \
            accA.y += bf2f((unsigned short)(v.x >> 16));                 \
            accA.z += bf2f((unsigned short)(v.y & 0xFFFF));              \
            accA.w += bf2f((unsigned short)(v.y >> 16));                 \
            accB.x += bf2f((unsigned short)(v.z & 0xFFFF));              \
            accB.y += bf2f((unsigned short)(v.z >> 16));                 \
            accB.z += bf2f((unsigned short)(v.w & 0xFFFF));              \
            accB.w += bf2f((unsigned short)(v.w >> 16));
            ACC8(v0) ACC8(v1) ACC8(v2) ACC8(v3)
        }
        for (; e < a1; ++e) {
            uint4 v0 = g4[(long)srt[e] * 8 + part];
            ACC8(v0)
        }
#undef ACC8
        float* op = out + (long)(node0 + grp) * DIM + part * 8;
        *(float4*)op = accA;
        *(float4*)(op + 4) = accB;
    }
}

extern "C" void kernel_launch(void* const* d_in, const int* in_sizes, int n_in,
                              void* d_out, int out_size, void* d_ws, size_t ws_size,
                              hipStream_t stream) {
    const float* feat = (const float*)d_in[0];
    const int*   src  = (const int*)d_in[1];
    const int*   dst  = (const int*)d_in[2];
    const float* W    = (const float*)d_in[3];
    const float* b    = (const float*)d_in[4];
    float* out = (float*)d_out;

    int n_nodes = in_sizes[0] / DIM;
    int n_edges = in_sizes[1];
    int nslab = (n_nodes + SLAB_NODES - 1) / SLAB_NODES;   // 1563

    // workspace: g bf16 (12.8 MB), cursors (6.4 KB), packed slots (6.55 MB)
    char* ws = (char*)d_ws;
    size_t off = 0;
    unsigned short* g = (unsigned short*)(ws + off);
    off += ((size_t)n_nodes * DIM * 2 + 255) & ~(size_t)255;
    int* cursors = (int*)(ws + off);
    off += ((size_t)MAX_SLABS * 4 + 255) & ~(size_t)255;
    unsigned int* packed = (unsigned int*)(ws + off);      // MAX_SLABS*SLAB_CAP u32

    zero_cursors<<<(MAX_SLABS + 255) / 256, 256, 0, stream>>>(cursors);
    int ntiles = (n_edges + PART_T - 1) / PART_T;          // 489
    int tblocks = (n_nodes + 63) / 64;                     // 1563
    prep_kernel<<<ntiles + tblocks, 256, 0, stream>>>(
        feat, W, g, src, dst, cursors, packed, n_nodes, n_edges, ntiles);
    slab_gather<<<nslab, 512, 0, stream>>>(g, cursors, packed, b, out, n_nodes);
}

// Round 17
// 58.627 us; speedup vs baseline: 1.3063x; 1.3063x over previous
//
#include <hip/hip_runtime.h>

// GNN layer: out = segment_sum(feat[src], dst) @ W^T + b
// Round 17: tile-major partition (atomic-free globally, no write
// amplification).  Round-16 counters showed partition WRITE_SIZE 2x expected:
// per-slab slot scatter dirtied a 64B line per ~5-entry run.  Now each
// partition block sorts its 8192-edge tile by slab into ITS OWN contiguous
// packed region (one writer, fully covered -> no amplification) and emits
// meta[t][slab] = tile_local_off<<16 | cnt.  Gather assembles its slab from
// the ~123 per-tile runs (cheap L2 reads), then counting-sorts as before.
// No cursors, no zero kernel, no global atomics anywhere in partition.

#define DIM 64
#define SLAB_SHIFT 6
#define SLAB_NODES 64
#define MAX_SLABS 1600    // >= ceil(100000/64) = 1563
#define SLAB_CAP 1024     // gather staging capacity (avg 640, +20 sigma)
#define PART_T 8192       // edges per partition tile (123 tiles)
#define MAX_TILES 128     // >= ceil(1e6/8192) = 123

typedef __attribute__((ext_vector_type(8))) short bf16x8;
typedef __attribute__((ext_vector_type(4))) float f32x4;

__device__ __forceinline__ unsigned short f2bf(float x) {
    unsigned u = __float_as_uint(x);
    unsigned r = ((u >> 16) & 1u) + 0x7FFFu;     // round-to-nearest-even
    return (unsigned short)((u + r) >> 16);
}
__device__ __forceinline__ float bf2f(unsigned short h) {
    return __uint_as_float((unsigned)h << 16);
}
// Load 8 consecutive f32, convert to a bf16x8 MFMA fragment.
__device__ __forceinline__ bf16x8 cvt8(const float* p) {
    float4 x = *(const float4*)p;
    float4 y = *(const float4*)(p + 4);
    bf16x8 r;
    r[0] = (short)f2bf(x.x); r[1] = (short)f2bf(x.y);
    r[2] = (short)f2bf(x.z); r[3] = (short)f2bf(x.w);
    r[4] = (short)f2bf(y.x); r[5] = (short)f2bf(y.y);
    r[6] = (short)f2bf(y.z); r[7] = (short)f2bf(y.w);
    return r;
}

// Fat kernel: partition (blocks < ntiles) / MFMA transform (blocks >= ntiles).
__global__ void __launch_bounds__(256, 4)
prep_kernel(const float* __restrict__ feat, const float* __restrict__ W,
            unsigned short* __restrict__ g,
            const int* __restrict__ src, const int* __restrict__ dst,
            unsigned int* __restrict__ meta, unsigned int* __restrict__ packed,
            int n_nodes, int n_edges, int ntiles) {
    __shared__ int cnt[MAX_SLABS];
    __shared__ int offs[MAX_SLABS];
    __shared__ int wsum[4];
    int tid = threadIdx.x;

    if (blockIdx.x < ntiles) {
        // ---------- partition: one 8192-edge tile, tile-major ----------
        int tile = blockIdx.x;
        int t0 = tile * PART_T;
        int m = min(PART_T, n_edges - t0);
        int m4 = m >> 2;
        int nslab = (n_nodes + SLAB_NODES - 1) / SLAB_NODES;
        for (int i = tid; i < nslab; i += 256) cnt[i] = 0;
        __syncthreads();
        // phase A: count
        const int4* d4 = (const int4*)(dst + t0);
        for (int i = tid; i < m4; i += 256) {
            int4 d = d4[i];
            atomicAdd(&cnt[d.x >> SLAB_SHIFT], 1);
            atomicAdd(&cnt[d.y >> SLAB_SHIFT], 1);
            atomicAdd(&cnt[d.z >> SLAB_SHIFT], 1);
            atomicAdd(&cnt[d.w >> SLAB_SHIFT], 1);
        }
        if (tid < (m & 3)) atomicAdd(&cnt[dst[t0 + (m4 << 2) + tid] >> SLAB_SHIFT], 1);
        __syncthreads();
        // phase B: block-exclusive scan of nslab counts (7 bins/thread).
        int tbase = tid * 7;
        int loc[7];
        int lsum = 0;
#pragma unroll
        for (int j = 0; j < 7; ++j) {
            int bin = tbase + j;
            int c = (bin < nslab) ? cnt[bin] : 0;
            loc[j] = lsum;
            lsum += c;
        }
        int lane = tid & 63, wv = tid >> 6;
        int incl = lsum;
#pragma unroll
        for (int o = 1; o < 64; o <<= 1) {
            int x = __shfl_up(incl, o, 64);
            if (lane >= o) incl += x;
        }
        if (lane == 63) wsum[wv] = incl;
        __syncthreads();
        int woff = 0;
        for (int k = 0; k < wv; ++k) woff += wsum[k];
        int base = woff + incl - lsum;       // block-exclusive thread base
        unsigned int* mrow = meta + (long)tile * nslab;
#pragma unroll
        for (int j = 0; j < 7; ++j) {
            int bin = tbase + j;
            if (bin < nslab) {
                int c = cnt[bin];
                int o = base + loc[j];
                mrow[bin] = ((unsigned)o << 16) | (unsigned)c;
                offs[bin] = o;               // running cursor for phase C
            }
        }
        __syncthreads();
        // phase C: scatter into OWN tile region (no global atomics).
        const int4* s4 = (const int4*)(src + t0);
        unsigned int* preg = packed + (long)tile * PART_T;
        for (int i = tid; i < m4; i += 256) {
            int4 d = d4[i];
            int4 s = s4[i];
            int sl, p;
            sl = d.x >> SLAB_SHIFT; p = atomicAdd(&offs[sl], 1);
            preg[p] = ((unsigned)(d.x & (SLAB_NODES - 1)) << 25) | (unsigned)s.x;
            sl = d.y >> SLAB_SHIFT; p = atomicAdd(&offs[sl], 1);
            preg[p] = ((unsigned)(d.y & (SLAB_NODES - 1)) << 25) | (unsigned)s.y;
            sl = d.z >> SLAB_SHIFT; p = atomicAdd(&offs[sl], 1);
            preg[p] = ((unsigned)(d.z & (SLAB_NODES - 1)) << 25) | (unsigned)s.z;
            sl = d.w >> SLAB_SHIFT; p = atomicAdd(&offs[sl], 1);
            preg[p] = ((unsigned)(d.w & (SLAB_NODES - 1)) << 25) | (unsigned)s.w;
        }
        if (tid < (m & 3)) {
            int e = t0 + (m4 << 2) + tid;
            int d = dst[e];
            int sl = d >> SLAB_SHIFT;
            int p = atomicAdd(&offs[sl], 1);
            preg[p] = ((unsigned)(d & (SLAB_NODES - 1)) << 25) | (unsigned)src[e];
        }
    } else {
        // -------- transform: 64 rows per block, MFMA, no LDS --------
        // A = W rows (m = output col o), B = feat rows (n = node).
        // D frag: n(node)=lane&15, m(o)=(lane>>4)*4+reg -> ushort4 stores.
        int ttile = blockIdx.x - ntiles;
        int lane = tid & 63;
        int wv2 = tid >> 6;
        int base_node = ttile * 64 + wv2 * 16;
        int rl = lane & 15;
        int kb = (lane >> 4) * 8;

        int node = base_node + rl;
        bf16x8 bLo, bHi;
        if (node < n_nodes) {
            const float* fr = feat + (long)node * DIM;
            bLo = cvt8(fr + kb);
            bHi = cvt8(fr + kb + 32);
        } else {
            bf16x8 z = {0, 0, 0, 0, 0, 0, 0, 0};
            bLo = z; bHi = z;
        }

        unsigned short* gp = g + (long)node * DIM + (lane >> 4) * 4;
#pragma unroll
        for (int t = 0; t < 4; ++t) {
            const float* wr = W + (long)(t * 16 + rl) * DIM;
            bf16x8 aLo = cvt8(wr + kb);
            bf16x8 aHi = cvt8(wr + kb + 32);
            f32x4 c = {0.f, 0.f, 0.f, 0.f};
            c = __builtin_amdgcn_mfma_f32_16x16x32_bf16(aLo, bLo, c, 0, 0, 0);
            c = __builtin_amdgcn_mfma_f32_16x16x32_bf16(aHi, bHi, c, 0, 0, 0);
            if (node < n_nodes) {
                ushort4 o4;
                o4.x = f2bf(c[0]); o4.y = f2bf(c[1]);
                o4.z = f2bf(c[2]); o4.w = f2bf(c[3]);
                *(ushort4*)(gp + t * 16) = o4;
            }
        }
    }
}

// One block per 64-node slab.  Assemble the slab's edges from per-tile runs
// (meta), then LDS counting-sort by exact dst (shfl scan) + owner-computes
// gather (8-lane groups, uint4 = 8 bf16/lane, unroll 4), + bias.
__global__ void __launch_bounds__(512, 8)
slab_gather(const unsigned short* __restrict__ g,
            const unsigned int* __restrict__ meta,
            const unsigned int* __restrict__ packed,
            const float* __restrict__ b, float* __restrict__ out,
            int n_nodes, int ntiles, int nslab) {
    __shared__ unsigned int raw[SLAB_CAP];
    __shared__ int srt[SLAB_CAP];
    __shared__ int cnt[SLAB_NODES];
    __shared__ int lstarts[SLAB_NODES + 1];
    __shared__ int sc[MAX_TILES];
    __shared__ int runDst[MAX_TILES];
    __shared__ int runSrc[MAX_TILES];
    __shared__ int runCnt[MAX_TILES];
    __shared__ int ceS;
    int tid = threadIdx.x;
    int slab = blockIdx.x;

    // phase 1: read per-tile meta, scan run lengths.
    int c_t = 0, o_t = 0;
    if (tid < ntiles) {
        unsigned int mt = meta[(long)tid * nslab + slab];
        c_t = (int)(mt & 0xFFFFu);
        o_t = (int)(mt >> 16);
    }
    if (tid < MAX_TILES) sc[tid] = c_t;      // zero beyond ntiles (c_t=0)
    __syncthreads();
    for (int off = 1; off < MAX_TILES; off <<= 1) {
        int x = 0;
        if (tid < MAX_TILES && tid >= off) x = sc[tid - off];
        __syncthreads();
        if (tid < MAX_TILES) sc[tid] += x;
        __syncthreads();
    }
    if (tid < ntiles) {
        runDst[tid] = sc[tid] - c_t;         // exclusive
        runSrc[tid] = tid * PART_T + o_t;
        runCnt[tid] = c_t;
    }
    if (tid == 0) ceS = min(sc[MAX_TILES - 1], SLAB_CAP);
    if (tid < SLAB_NODES) cnt[tid] = 0;
    __syncthreads();
    int ce = ceS;

    // phase 2: copy runs into raw[] (4 lanes per tile).
    {
        int t = tid >> 2, j = tid & 3;
        if (t < ntiles) {
            int rc = runCnt[t], rd = runDst[t], rs = runSrc[t];
            for (int k = j; k < rc; k += 4) {
                int p = rd + k;
                if (p < SLAB_CAP) raw[p] = packed[rs + k];
            }
        }
    }
    __syncthreads();

    // phase 3: counting sort by exact dst-low.
    for (int k = tid; k < ce; k += 512) atomicAdd(&cnt[raw[k] >> 25], 1);
    __syncthreads();
    if (tid < 64) {
        int v = cnt[tid];
        int orig = v;
#pragma unroll
        for (int off = 1; off < 64; off <<= 1) {
            int x = __shfl_up(v, off, 64);
            v += (tid >= off) ? x : 0;
        }
        lstarts[tid + 1] = v;
        cnt[tid] = v - orig;
        if (tid == 0) lstarts[0] = 0;
    }
    __syncthreads();
    for (int k = tid; k < ce; k += 512) {
        unsigned int v = raw[k];
        int nl = (int)(v >> 25);
        int p = atomicAdd(&cnt[nl], 1);
        srt[p] = (int)(v & 0x1FFFFFFu);
    }
    __syncthreads();

    // phase 4: gather + bias + writeout.
    int grp = tid >> 3;      // 0..63: owns node `grp`
    int part = tid & 7;      // uint4 chunk (8 bf16 columns)
    int node0 = slab * SLAB_NODES;
    int nsn = min(SLAB_NODES, n_nodes - node0);
    const uint4* g4 = (const uint4*)g;

    if (grp < nsn) {
        float4 accA = *(const float4*)(b + part * 8);
        float4 accB = *(const float4*)(b + part * 8 + 4);
        int a0 = lstarts[grp], a1 = lstarts[grp + 1];
        int e = a0;
        for (; e + 3 < a1; e += 4) {
            uint4 v0 = g4[(long)srt[e]     * 8 + part];
            uint4 v1 = g4[(long)srt[e + 1] * 8 + part];
            uint4 v2 = g4[(long)srt[e + 2] * 8 + part];
            uint4 v3 = g4[(long)srt[e + 3] * 8 + part];
#define ACC8(v)                                                          \
            accA.x += bf2f((unsigned short)(v.x & 0xFFFF));              \
            accA.y += bf2f((unsigned short)(v.x >> 16));                 \
            accA.z += bf2f((unsigned short)(v.y & 0xFFFF));              \
            accA.w += bf2f((unsigned short)(v.y >> 16));                 \
            accB.x += bf2f((unsigned short)(v.z & 0xFFFF));              \
            accB.y += bf2f((unsigned short)(v.z >> 16));                 \
            accB.z += bf2f((unsigned short)(v.w & 0xFFFF));              \
            accB.w += bf2f((unsigned short)(v.w >> 16));
            ACC8(v0) ACC8(v1) ACC8(v2) ACC8(v3)
        }
        for (; e < a1; ++e) {
            uint4 v0 = g4[(long)srt[e] * 8 + part];
            ACC8(v0)
        }
#undef ACC8
        float* op = out + (long)(node0 + grp) * DIM + part * 8;
        *(float4*)op = accA;
        *(float4*)(op + 4) = accB;
    }
}

extern "C" void kernel_launch(void* const* d_in, const int* in_sizes, int n_in,
                              void* d_out, int out_size, void* d_ws, size_t ws_size,
                              hipStream_t stream) {
    const float* feat = (const float*)d_in[0];
    const int*   src  = (const int*)d_in[1];
    const int*   dst  = (const int*)d_in[2];
    const float* W    = (const float*)d_in[3];
    const float* b    = (const float*)d_in[4];
    float* out = (float*)d_out;

    int n_nodes = in_sizes[0] / DIM;
    int n_edges = in_sizes[1];
    int nslab = (n_nodes + SLAB_NODES - 1) / SLAB_NODES;   // 1563
    int ntiles = (n_edges + PART_T - 1) / PART_T;          // 123

    // workspace: g bf16 (12.8 MB), meta (769 KB), packed (4.03 MB)
    char* ws = (char*)d_ws;
    size_t off = 0;
    unsigned short* g = (unsigned short*)(ws + off);
    off += ((size_t)n_nodes * DIM * 2 + 255) & ~(size_t)255;
    unsigned int* meta = (unsigned int*)(ws + off);
    off += ((size_t)ntiles * nslab * 4 + 255) & ~(size_t)255;
    unsigned int* packed = (unsigned int*)(ws + off);      // ntiles*PART_T u32

    int tblocks = (n_nodes + 63) / 64;                     // 1563
    prep_kernel<<<ntiles + tblocks, 256, 0, stream>>>(
        feat, W, g, src, dst, meta, packed, n_nodes, n_edges, ntiles);
    slab_gather<<<nslab, 512, 0, stream>>>(g, meta, packed, b, out,
                                           n_nodes, ntiles, nslab);
}